// Round 7
// baseline (201.483 us; speedup 1.0000x reference)
//
#include <hip/hip_runtime.h>
#include <hip/hip_bf16.h>
#include <cstddef>

#define E_DIM  768
#define S_LEN  1024
#define NHEADS 12
#define HDIM   64
#define BATCH  8
#define TOKENS (BATCH * S_LEN)
#define WELEMS (E_DIM * E_DIM)   // 589824

typedef short bf16x8 __attribute__((ext_vector_type(8)));
typedef short bf16x4 __attribute__((ext_vector_type(4)));
typedef float f32x4  __attribute__((ext_vector_type(4)));

#define MFMA16(a, b, c)   __builtin_amdgcn_mfma_f32_16x16x32_bf16((a), (b), (c), 0, 0, 0)
// K=16 variant: A/B = 4 bf16 (2 VGPRs), lane layout k = quad*4 + j  == C/D row layout
#define MFMA16K16(a, b, c) __builtin_amdgcn_mfma_f32_16x16x16bf16_1k((a), (b), (c), 0, 0, 0)

// direct-to-LDS 16B async copy (dest = wave-uniform base + lane*16)
#define GLD_LDS16(gp, lp)                                                  \
    __builtin_amdgcn_global_load_lds(                                      \
        (const __attribute__((address_space(1))) void*)(gp),               \
        (__attribute__((address_space(3))) void*)(lp), 16, 0, 0)

// exp(s/8) = exp2(s * 0.125*log2(e)); scale folded into stored Q
#define QSCALE 0.180336880f

static __device__ __forceinline__ short f2bf(float f) {
    union { float f; unsigned int u; } cv; cv.f = f;
    unsigned int u = cv.u + 0x7fffu + ((cv.u >> 16) & 1u);  // RNE
    return (short)(u >> 16);
}

// ---------------------------------------------------------------------------
// X[8192,768] f32 -> bf16, streaming. One 8-elem group per thread.
// ---------------------------------------------------------------------------
__global__ __launch_bounds__(256) void xcvt_kernel(
    const float* __restrict__ X, short* __restrict__ Y)
{
    const size_t i = ((size_t)blockIdx.x * 256 + threadIdx.x) * 8;
    const float4 a = *(const float4*)&X[i];
    const float4 b = *(const float4*)&X[i + 4];
    bf16x8 o;
    o[0] = f2bf(a.x); o[1] = f2bf(a.y); o[2] = f2bf(a.z); o[3] = f2bf(a.w);
    o[4] = f2bf(b.x); o[5] = f2bf(b.y); o[6] = f2bf(b.z); o[7] = f2bf(b.w);
    *(bf16x8*)&Y[i] = o;
}

// ---------------------------------------------------------------------------
// W[768,768] f32 -> Wt bf16 with Wt[n][k] = W[k][n]; z selects source.
// ---------------------------------------------------------------------------
__global__ __launch_bounds__(256) void transpose_w(
    const float* __restrict__ s0, const float* __restrict__ s1,
    const float* __restrict__ s2, const float* __restrict__ s3,
    short* __restrict__ dst)
{
    const int z = blockIdx.z;
    const float* S = (z == 0) ? s0 : (z == 1) ? s1 : (z == 2) ? s2 : s3;
    short* D = dst + (size_t)z * WELEMS;
    __shared__ float t[64][65];
    const int r = threadIdx.x >> 2, c0 = (threadIdx.x & 3) * 16;
    const int br = blockIdx.x * 64, bc = blockIdx.y * 64;
    #pragma unroll
    for (int j = 0; j < 4; ++j) {
        float4 v = *(const float4*)&S[(size_t)(br + r) * E_DIM + bc + c0 + j * 4];
        t[r][c0 + j * 4 + 0] = v.x; t[r][c0 + j * 4 + 1] = v.y;
        t[r][c0 + j * 4 + 2] = v.z; t[r][c0 + j * 4 + 3] = v.w;
    }
    __syncthreads();
    #pragma unroll
    for (int half = 0; half < 2; ++half) {
        bf16x8 o;
        #pragma unroll
        for (int j = 0; j < 8; ++j) o[j] = f2bf(t[c0 + half * 8 + j][r]);
        *(bf16x8*)&D[(size_t)(bc + r) * E_DIM + br + c0 + half * 8] = o;
    }
}

// ---------------------------------------------------------------------------
// Fused QKV GEMM: A[8192,768] @ Wt^T + b. 128x128 tile, BK=64, 4 waves.
// AF32=false: A bf16 via global_load_lds. AF32=true: f32 reg-staged (fallback).
// wsel 0: Q -> [B,H,S,D] scaled QSCALE; 1: K -> [B,H,S,D]; 2: V -> [B,H,D,S]
// ---------------------------------------------------------------------------
template<bool AF32>
__global__ __launch_bounds__(256, 3) void gemm_qkv_t(
    const void* __restrict__ Ap, const short* __restrict__ Wt,
    const float* __restrict__ bq, const float* __restrict__ bk,
    const float* __restrict__ bv, short* __restrict__ oq,
    short* __restrict__ ok, short* __restrict__ ov)
{
    __shared__ __align__(16) short As[128 * 64];
    __shared__ __align__(16) short Bs[128 * 64];

    const int tid  = threadIdx.x;
    const int wave = tid >> 6, lane = tid & 63;
    const int quad = lane >> 4, l16 = lane & 15;
    const int bm = blockIdx.x * 128;
    const int by = blockIdx.y;
    const int wsel = by / 6;                 // 0=Q 1=K 2=V (uniform)
    const int nb = (by % 6) * 128;
    const short* wt = Wt + (size_t)wsel * WELEMS;
    const float* bias = (wsel == 0) ? bq : (wsel == 1) ? bk : bv;
    short* outp = (wsel == 0) ? oq : (wsel == 1) ? ok : ov;
    const int wm = (wave >> 1) * 64, wn = (wave & 1) * 64;

    f32x4 acc[4][4];
    #pragma unroll
    for (int mt = 0; mt < 4; ++mt)
        #pragma unroll
        for (int nt = 0; nt < 4; ++nt) acc[mt][nt] = (f32x4){0.f, 0.f, 0.f, 0.f};

    for (int k0 = 0; k0 < E_DIM; k0 += 64) {
        if (AF32) {
            const float* A = (const float*)Ap;
            float4 ax[4][2];
            #pragma unroll
            for (int i = 0; i < 4; ++i) {
                const int slot = i * 256 + tid;
                const int row = slot >> 3, cl = slot & 7;
                const float4* gp = (const float4*)&A[(size_t)(bm + row) * E_DIM + k0 + cl * 8];
                ax[i][0] = gp[0]; ax[i][1] = gp[1];
            }
            __syncthreads();
            #pragma unroll
            for (int i = 0; i < 4; ++i) {
                const int slot = i * 256 + tid;
                const int row = slot >> 3, cl = slot & 7, cg = cl ^ (row & 7);
                GLD_LDS16(&wt[(size_t)(nb + row) * E_DIM + k0 + cg * 8], &Bs[slot * 8]);
            }
            #pragma unroll
            for (int i = 0; i < 4; ++i) {
                const int slot = i * 256 + tid;
                const int row = slot >> 3, cl = slot & 7, cs = cl ^ (row & 7);
                bf16x8 v8;
                v8[0] = f2bf(ax[i][0].x); v8[1] = f2bf(ax[i][0].y);
                v8[2] = f2bf(ax[i][0].z); v8[3] = f2bf(ax[i][0].w);
                v8[4] = f2bf(ax[i][1].x); v8[5] = f2bf(ax[i][1].y);
                v8[6] = f2bf(ax[i][1].z); v8[7] = f2bf(ax[i][1].w);
                *(bf16x8*)&As[row * 64 + cs * 8] = v8;
            }
        } else {
            const short* A = (const short*)Ap;
            __syncthreads();
            #pragma unroll
            for (int i = 0; i < 4; ++i) {
                const int slot = i * 256 + tid;
                const int row = slot >> 3, cl = slot & 7, cg = cl ^ (row & 7);
                GLD_LDS16(&A[(size_t)(bm + row) * E_DIM + k0 + cg * 8], &As[slot * 8]);
            }
            #pragma unroll
            for (int i = 0; i < 4; ++i) {
                const int slot = i * 256 + tid;
                const int row = slot >> 3, cl = slot & 7, cg = cl ^ (row & 7);
                GLD_LDS16(&wt[(size_t)(nb + row) * E_DIM + k0 + cg * 8], &Bs[slot * 8]);
            }
        }
        __syncthreads();

        #pragma unroll
        for (int ks = 0; ks < 2; ++ks) {
            bf16x8 a[4], b[4];
            #pragma unroll
            for (int mt = 0; mt < 4; ++mt) {
                const int row = wm + mt * 16 + l16;
                const int c = (ks * 4 + quad) ^ (row & 7);
                a[mt] = *(const bf16x8*)&As[row * 64 + c * 8];
            }
            #pragma unroll
            for (int nt = 0; nt < 4; ++nt) {
                const int row = wn + nt * 16 + l16;
                const int c = (ks * 4 + quad) ^ (row & 7);
                b[nt] = *(const bf16x8*)&Bs[row * 64 + c * 8];
            }
            #pragma unroll
            for (int mt = 0; mt < 4; ++mt)
                #pragma unroll
                for (int nt = 0; nt < 4; ++nt)
                    acc[mt][nt] = MFMA16(a[mt], b[nt], acc[mt][nt]);
        }
    }

    const float qscale = (wsel == 0) ? QSCALE : 1.0f;
    #pragma unroll
    for (int nt = 0; nt < 4; ++nt) {
        const int ncol = nb + wn + nt * 16 + l16;
        const float bvv = bias[ncol];
        const int h = ncol >> 6, d = ncol & (HDIM - 1);
        #pragma unroll
        for (int mt = 0; mt < 4; ++mt) {
            const int grow = bm + wm + mt * 16 + quad * 4;
            if (wsel < 2) {
                #pragma unroll
                for (int r = 0; r < 4; ++r) {
                    const int g = grow + r, b = g >> 10, s = g & (S_LEN - 1);
                    outp[((size_t)(b * NHEADS + h) * S_LEN + s) * HDIM + d] =
                        f2bf((acc[mt][nt][r] + bvv) * qscale);
                }
            } else {  // V: [B,H,D,S]; 4 r-values s-consecutive -> 8B packed
                const int b = grow >> 10, s0 = grow & (S_LEN - 1);
                bf16x4 pv;
                #pragma unroll
                for (int r = 0; r < 4; ++r) pv[r] = f2bf(acc[mt][nt][r] + bvv);
                *(bf16x4*)&outp[((size_t)(b * NHEADS + h) * HDIM + d) * S_LEN + s0] = pv;
            }
        }
    }
}

// ---------------------------------------------------------------------------
// Out projection: attn[8192,768] bf16 @ Wt_o^T + bo -> f32 out.
// ---------------------------------------------------------------------------
__global__ __launch_bounds__(256, 3) void gemm_out_kernel(
    const short* __restrict__ A, const short* __restrict__ Wt,
    const float* __restrict__ bias, float* __restrict__ out)
{
    __shared__ __align__(16) short As[128 * 64];
    __shared__ __align__(16) short Bs[128 * 64];

    const int tid  = threadIdx.x;
    const int wave = tid >> 6, lane = tid & 63;
    const int quad = lane >> 4, l16 = lane & 15;
    const int bm = blockIdx.x * 128, nb = blockIdx.y * 128;
    const int wm = (wave >> 1) * 64, wn = (wave & 1) * 64;

    f32x4 acc[4][4];
    #pragma unroll
    for (int mt = 0; mt < 4; ++mt)
        #pragma unroll
        for (int nt = 0; nt < 4; ++nt) acc[mt][nt] = (f32x4){0.f, 0.f, 0.f, 0.f};

    for (int k0 = 0; k0 < E_DIM; k0 += 64) {
        __syncthreads();
        #pragma unroll
        for (int i = 0; i < 4; ++i) {
            const int slot = i * 256 + tid;
            const int row = slot >> 3, cl = slot & 7, cg = cl ^ (row & 7);
            GLD_LDS16(&A[(size_t)(bm + row) * E_DIM + k0 + cg * 8], &As[slot * 8]);
        }
        #pragma unroll
        for (int i = 0; i < 4; ++i) {
            const int slot = i * 256 + tid;
            const int row = slot >> 3, cl = slot & 7, cg = cl ^ (row & 7);
            GLD_LDS16(&Wt[(size_t)(nb + row) * E_DIM + k0 + cg * 8], &Bs[slot * 8]);
        }
        __syncthreads();

        #pragma unroll
        for (int ks = 0; ks < 2; ++ks) {
            bf16x8 a[4], b[4];
            #pragma unroll
            for (int mt = 0; mt < 4; ++mt) {
                const int row = wm + mt * 16 + l16;
                const int c = (ks * 4 + quad) ^ (row & 7);
                a[mt] = *(const bf16x8*)&As[row * 64 + c * 8];
            }
            #pragma unroll
            for (int nt = 0; nt < 4; ++nt) {
                const int row = wn + nt * 16 + l16;
                const int c = (ks * 4 + quad) ^ (row & 7);
                b[nt] = *(const bf16x8*)&Bs[row * 64 + c * 8];
            }
            #pragma unroll
            for (int mt = 0; mt < 4; ++mt)
                #pragma unroll
                for (int nt = 0; nt < 4; ++nt)
                    acc[mt][nt] = MFMA16(a[mt], b[nt], acc[mt][nt]);
        }
    }

    #pragma unroll
    for (int nt = 0; nt < 4; ++nt) {
        const int ncol = nb + wn + nt * 16 + l16;
        const float bvv = bias[ncol];
        #pragma unroll
        for (int mt = 0; mt < 4; ++mt) {
            const int grow = bm + wm + mt * 16 + quad * 4;
            #pragma unroll
            for (int r = 0; r < 4; ++r)
                out[(size_t)(grow + r) * E_DIM + ncol] = acc[mt][nt][r] + bvv;
        }
    }
}

// ---------------------------------------------------------------------------
// Flash attention, S^T formulation + double-buffered prefetch pipeline.
// grid(96, 8): blockIdx.x = head -> all 8 q-blocks of a head share an XCD
// (round-robin conjecture; perf heuristic only). DMA for tile i+1 is issued
// AFTER the barrier and overlaps compute of tile i (issue-after-barrier
// shape; the old sync;DMA;sync;compute form exposed full staging latency).
// Q pre-scaled by 0.125*log2(e) -> P = exp2(S) via raw v_exp_f32.
// ---------------------------------------------------------------------------
__global__ __launch_bounds__(256) void attn_kernel(
    const short* __restrict__ Q, const short* __restrict__ K,
    const short* __restrict__ V, short* __restrict__ O)
{
    __shared__ __align__(16) short Ks[2][64 * 64];   // swizzled, DMA-staged
    __shared__ __align__(16) short Vt[2][64 * 64];   // swizzled, DMA-staged

    const int tid  = threadIdx.x;
    const int wave = tid >> 6, lane = tid & 63;
    const int quad = lane >> 4, l16 = lane & 15;
    const int bh = blockIdx.x;            // head-major for XCD L2 locality
    const int q0 = blockIdx.y * 128;
    const size_t base = (size_t)bh * S_LEN * HDIM;
    const short* Qb = Q + base;
    const short* Kb = K + base;
    const short* Vb = V + base;   // [d][s] per head

    // Q fragments from global; used as the B operand of S^T = K·Q^T
    bf16x8 qa[2][2];
    #pragma unroll
    for (int mt = 0; mt < 2; ++mt)
        #pragma unroll
        for (int ks = 0; ks < 2; ++ks)
            qa[mt][ks] = *(const bf16x8*)&Qb[
                (size_t)(q0 + wave * 32 + mt * 16 + l16) * HDIM + ks * 32 + quad * 8];

    bf16x4 ones4;
    #pragma unroll
    for (int j = 0; j < 4; ++j) ones4[j] = (short)0x3F80;   // bf16 1.0

    f32x4 oacc[2][4], lacc[2];
    #pragma unroll
    for (int mt = 0; mt < 2; ++mt) {
        #pragma unroll
        for (int nt = 0; nt < 4; ++nt) oacc[mt][nt] = (f32x4){0.f, 0.f, 0.f, 0.f};
        lacc[mt] = (f32x4){0.f, 0.f, 0.f, 0.f};
    }

    // prefetch tile 0 into buffer 0
    #pragma unroll
    for (int i = 0; i < 2; ++i) {
        const int slot = i * 256 + tid;
        const int row = slot >> 3, cl = slot & 7, cg = cl ^ (row & 7);
        GLD_LDS16(&Kb[(size_t)row * HDIM + cg * 8], &Ks[0][slot * 8]);
        GLD_LDS16(&Vb[(size_t)row * S_LEN + cg * 8], &Vt[0][slot * 8]);
    }

    for (int it = 0; it < S_LEN / 64; ++it) {
        __syncthreads();   // drains DMA(tile it); prior compute reads done
        if (it + 1 < S_LEN / 64) {       // prefetch tile it+1 (overlaps compute)
            const int kt = (it + 1) * 64, nb = (it + 1) & 1;
            #pragma unroll
            for (int i = 0; i < 2; ++i) {
                const int slot = i * 256 + tid;
                const int row = slot >> 3, cl = slot & 7, cg = cl ^ (row & 7);
                GLD_LDS16(&Kb[(size_t)(kt + row) * HDIM + cg * 8], &Ks[nb][slot * 8]);
                GLD_LDS16(&Vb[(size_t)row * S_LEN + kt + cg * 8], &Vt[nb][slot * 8]);
            }
        }
        const short* ksb = Ks[it & 1];
        const short* vtb = Vt[it & 1];

        // S^T[key][q] = K·Q^T : A = K-frag (m=key), B = Q-frag (n=q)
        f32x4 sc[2][4];   // [mt][key-tile t]
        #pragma unroll
        for (int mt = 0; mt < 2; ++mt)
            #pragma unroll
            for (int t = 0; t < 4; ++t) sc[mt][t] = (f32x4){0.f, 0.f, 0.f, 0.f};
        #pragma unroll
        for (int ks = 0; ks < 2; ++ks)
            #pragma unroll
            for (int t = 0; t < 4; ++t) {
                const int row = t * 16 + l16;
                const int c = (ks * 4 + quad) ^ (row & 7);
                const bf16x8 kf = *(const bf16x8*)&ksb[row * 64 + c * 8];
                #pragma unroll
                for (int mt = 0; mt < 2; ++mt)
                    sc[mt][t] = MFMA16(kf, qa[mt][ks], sc[mt][t]);
            }

        // P = exp2(S^T) packed in-register (C/D row layout == K=16 A-frag k)
        bf16x4 pa16[2][4];
        #pragma unroll
        for (int mt = 0; mt < 2; ++mt)
            #pragma unroll
            for (int t = 0; t < 4; ++t)
                #pragma unroll
                for (int r = 0; r < 4; ++r)
                    pa16[mt][t][r] = f2bf(__builtin_amdgcn_exp2f(sc[mt][t][r]));

        // O += P·V and l += P·1 via 16x16x16 MFMA (4 key-chunks of 16)
        #pragma unroll
        for (int t = 0; t < 4; ++t) {
            #pragma unroll
            for (int mt = 0; mt < 2; ++mt)
                lacc[mt] = MFMA16K16(pa16[mt][t], ones4, lacc[mt]);
            #pragma unroll
            for (int nt = 0; nt < 4; ++nt) {
                const int row = nt * 16 + l16;                    // d
                const int c = (t * 2 + (quad >> 1)) ^ (row & 7);  // swizzled chunk
                const bf16x4 vb = *(const bf16x4*)&vtb[row * 64 + c * 8 + (quad & 1) * 4];
                #pragma unroll
                for (int mt = 0; mt < 2; ++mt)
                    oacc[mt][nt] = MFMA16K16(pa16[mt][t], vb, oacc[mt][nt]);
            }
        }
    }

    const int b = bh / NHEADS, h = bh - b * NHEADS;
    #pragma unroll
    for (int mt = 0; mt < 2; ++mt)
        #pragma unroll
        for (int nt = 0; nt < 4; ++nt)
            #pragma unroll
            for (int r = 0; r < 4; ++r) {
                const int qrow = q0 + wave * 32 + mt * 16 + quad * 4 + r;
                const float val = oacc[mt][nt][r] / lacc[mt][r];
                O[(size_t)(b * S_LEN + qrow) * E_DIM + h * HDIM + nt * 16 + l16] = f2bf(val);
            }
}

extern "C" void kernel_launch(void* const* d_in, const int* in_sizes, int n_in,
                              void* d_out, int out_size, void* d_ws, size_t ws_size,
                              hipStream_t stream) {
    const float* X  = (const float*)d_in[0];
    const float* Wq = (const float*)d_in[1];
    const float* bq = (const float*)d_in[2];
    const float* Wk = (const float*)d_in[3];
    const float* bk = (const float*)d_in[4];
    const float* Wv = (const float*)d_in[5];
    const float* bv = (const float*)d_in[6];
    const float* Wo = (const float*)d_in[7];
    const float* bo = (const float*)d_in[8];
    float* out = (float*)d_out;

    const size_t t = (size_t)TOKENS * E_DIM;   // 6.29M elems
    short* q    = (short*)d_ws;
    short* k    = q + t;
    short* vT   = k + t;                       // [B,H,D,S]
    short* attn = vT + t;

    const size_t fast_need = (5 * t + 4 * (size_t)WELEMS) * 2;   // ~67.6 MB
    if (ws_size >= fast_need) {
        short* wt4 = attn + t;                 // Wq^T,Wk^T,Wv^T,Wo^T (bf16)
        short* xbf = wt4 + 4 * (size_t)WELEMS; // X in bf16
        xcvt_kernel<<<(TOKENS * E_DIM / 8) / 256, 256, 0, stream>>>(X, xbf);
        transpose_w<<<dim3(12, 12, 4), 256, 0, stream>>>(Wq, Wk, Wv, Wo, wt4);
        gemm_qkv_t<false><<<dim3(TOKENS / 128, 18), 256, 0, stream>>>(
            xbf, wt4, bq, bk, bv, q, k, vT);
        attn_kernel<<<dim3(BATCH * NHEADS, S_LEN / 128), 256, 0, stream>>>(q, k, vT, attn);
        gemm_out_kernel<<<dim3(TOKENS / 128, 6), 256, 0, stream>>>(
            attn, wt4 + 3 * (size_t)WELEMS, bo, out);
    } else {
        // fallback: round-3 layout, cvt inside QKV kernel (ws = 50.3 MB)
        short* wt_qkv = attn;                  // overwritten later by attn out
        short* wt_o   = q;                     // q consumed before out-GEMM
        transpose_w<<<dim3(12, 12, 3), 256, 0, stream>>>(Wq, Wk, Wv, Wv, wt_qkv);
        gemm_qkv_t<true><<<dim3(TOKENS / 128, 18), 256, 0, stream>>>(
            X, wt_qkv, bq, bk, bv, q, k, vT);
        attn_kernel<<<dim3(BATCH * NHEADS, S_LEN / 128), 256, 0, stream>>>(q, k, vT, attn);
        transpose_w<<<dim3(12, 12, 1), 256, 0, stream>>>(Wo, Wo, Wo, Wo, wt_o);
        gemm_out_kernel<<<dim3(TOKENS / 128, 6), 256, 0, stream>>>(attn, wt_o, bo, out);
    }
}

// Round 8
// 191.630 us; speedup vs baseline: 1.0514x; 1.0514x over previous
//
#include <hip/hip_runtime.h>
#include <hip/hip_bf16.h>
#include <cstddef>

#define E_DIM  768
#define S_LEN  1024
#define NHEADS 12
#define HDIM   64
#define BATCH  8
#define TOKENS (BATCH * S_LEN)
#define WELEMS (E_DIM * E_DIM)   // 589824

typedef short bf16x8 __attribute__((ext_vector_type(8)));
typedef short bf16x4 __attribute__((ext_vector_type(4)));
typedef float f32x4  __attribute__((ext_vector_type(4)));

#define MFMA16(a, b, c)   __builtin_amdgcn_mfma_f32_16x16x32_bf16((a), (b), (c), 0, 0, 0)
// K=16 variant: A/B = 4 bf16 (2 VGPRs), lane layout k = quad*4 + j == C/D row layout
#define MFMA16K16(a, b, c) __builtin_amdgcn_mfma_f32_16x16x16bf16_1k((a), (b), (c), 0, 0, 0)

// direct-to-LDS 16B async copy (dest = wave-uniform base + lane*16)
#define GLD_LDS16(gp, lp)                                                  \
    __builtin_amdgcn_global_load_lds(                                      \
        (const __attribute__((address_space(1))) void*)(gp),               \
        (__attribute__((address_space(3))) void*)(lp), 16, 0, 0)

// exp(s/8) = exp2(s * 0.125*log2(e)); scale folded into stored Q
#define QSCALE 0.180336880f

static __device__ __forceinline__ short f2bf(float f) {
    union { float f; unsigned int u; } cv; cv.f = f;
    unsigned int u = cv.u + 0x7fffu + ((cv.u >> 16) & 1u);  // RNE
    return (short)(u >> 16);
}

// pack two f32 -> bf16x2 (half-up rounding): 2 adds + 1 v_perm
static __device__ __forceinline__ unsigned int pk2(float f0, float f1) {
    union { float f; unsigned int u; } a, b;
    a.f = f0; b.f = f1;
    return __builtin_amdgcn_perm(b.u + 0x8000u, a.u + 0x8000u, 0x07060302u);
}
static __device__ __forceinline__ bf16x4 pk4(float f0, float f1, float f2, float f3) {
    union { unsigned int u[2]; bf16x4 v; } r;
    r.u[0] = pk2(f0, f1); r.u[1] = pk2(f2, f3);
    return r.v;
}

// ---------------------------------------------------------------------------
// X[8192,768] f32 -> bf16, streaming.
// ---------------------------------------------------------------------------
__global__ __launch_bounds__(256) void xcvt_kernel(
    const float* __restrict__ X, short* __restrict__ Y)
{
    const size_t i = ((size_t)blockIdx.x * 256 + threadIdx.x) * 8;
    const float4 a = *(const float4*)&X[i];
    const float4 b = *(const float4*)&X[i + 4];
    union { unsigned int u[4]; bf16x8 v; } o;
    o.u[0] = pk2(a.x, a.y); o.u[1] = pk2(a.z, a.w);
    o.u[2] = pk2(b.x, b.y); o.u[3] = pk2(b.z, b.w);
    *(bf16x8*)&Y[i] = o.v;
}

// ---------------------------------------------------------------------------
// W[768,768] f32 -> Wt bf16 with Wt[n][k] = W[k][n]; z selects source.
// ---------------------------------------------------------------------------
__global__ __launch_bounds__(256) void transpose_w(
    const float* __restrict__ s0, const float* __restrict__ s1,
    const float* __restrict__ s2, const float* __restrict__ s3,
    short* __restrict__ dst)
{
    const int z = blockIdx.z;
    const float* S = (z == 0) ? s0 : (z == 1) ? s1 : (z == 2) ? s2 : s3;
    short* D = dst + (size_t)z * WELEMS;
    __shared__ float t[64][65];
    const int r = threadIdx.x >> 2, c0 = (threadIdx.x & 3) * 16;
    const int br = blockIdx.x * 64, bc = blockIdx.y * 64;
    #pragma unroll
    for (int j = 0; j < 4; ++j) {
        float4 v = *(const float4*)&S[(size_t)(br + r) * E_DIM + bc + c0 + j * 4];
        t[r][c0 + j * 4 + 0] = v.x; t[r][c0 + j * 4 + 1] = v.y;
        t[r][c0 + j * 4 + 2] = v.z; t[r][c0 + j * 4 + 3] = v.w;
    }
    __syncthreads();
    #pragma unroll
    for (int half = 0; half < 2; ++half) {
        union { unsigned int u[2]; bf16x4 v; } o0, o1;
        o0.u[0] = pk2(t[c0 + half * 8 + 0][r], t[c0 + half * 8 + 1][r]);
        o0.u[1] = pk2(t[c0 + half * 8 + 2][r], t[c0 + half * 8 + 3][r]);
        o1.u[0] = pk2(t[c0 + half * 8 + 4][r], t[c0 + half * 8 + 5][r]);
        o1.u[1] = pk2(t[c0 + half * 8 + 6][r], t[c0 + half * 8 + 7][r]);
        *(bf16x4*)&D[(size_t)(bc + r) * E_DIM + br + c0 + half * 8]     = o0.v;
        *(bf16x4*)&D[(size_t)(bc + r) * E_DIM + br + c0 + half * 8 + 4] = o1.v;
    }
}

// ---------------------------------------------------------------------------
// Fused QKV GEMM: A[8192,768] @ Wt^T + b. 128x128 tile, BK=64, 4 waves.
// 1D grid, XCD-aware: x=bid&7 selects XCD (bid%8 round-robin, verified by
// attn r7 FETCH collapse); per XCD n-major/m-minor => 8 X-strips (1.57 MB)
// L2-resident + weight strip streamed once while hot.
// wsel 0: Q -> [B,H,D,S] scaled QSCALE (transposed!); 1: K -> [B,H,S,D];
// wsel 2: V -> [B,H,D,S].
// ---------------------------------------------------------------------------
template<bool AF32>
__global__ __launch_bounds__(256, 3) void gemm_qkv_t(
    const void* __restrict__ Ap, const short* __restrict__ Wt,
    const float* __restrict__ bq, const float* __restrict__ bk,
    const float* __restrict__ bv, short* __restrict__ oq,
    short* __restrict__ ok, short* __restrict__ ov)
{
    __shared__ __align__(16) short As[128 * 64];
    __shared__ __align__(16) short Bs[128 * 64];

    const int tid  = threadIdx.x;
    const int wave = tid >> 6, lane = tid & 63;
    const int quad = lane >> 4, l16 = lane & 15;
    // XCD-aware decode: 1152 blocks = 18 n-strips x 64 m-strips
    const int bid = blockIdx.x;
    const int xcd = bid & 7, qq = bid >> 3;       // qq 0..143
    const int nblk = qq >> 3;                     // 0..17, n-major within XCD
    const int bm = (xcd * 8 + (qq & 7)) * 128;
    const int wsel = nblk / 6;                    // 0=Q 1=K 2=V (uniform)
    const int nb = (nblk % 6) * 128;
    const short* wt = Wt + (size_t)wsel * WELEMS;
    const float* bias = (wsel == 0) ? bq : (wsel == 1) ? bk : bv;
    short* outp = (wsel == 0) ? oq : (wsel == 1) ? ok : ov;
    const int wm = (wave >> 1) * 64, wn = (wave & 1) * 64;

    f32x4 acc[4][4];
    #pragma unroll
    for (int mt = 0; mt < 4; ++mt)
        #pragma unroll
        for (int nt = 0; nt < 4; ++nt) acc[mt][nt] = (f32x4){0.f, 0.f, 0.f, 0.f};

    for (int k0 = 0; k0 < E_DIM; k0 += 64) {
        if (AF32) {
            const float* A = (const float*)Ap;
            float4 ax[4][2];
            #pragma unroll
            for (int i = 0; i < 4; ++i) {
                const int slot = i * 256 + tid;
                const int row = slot >> 3, cl = slot & 7;
                const float4* gp = (const float4*)&A[(size_t)(bm + row) * E_DIM + k0 + cl * 8];
                ax[i][0] = gp[0]; ax[i][1] = gp[1];
            }
            __syncthreads();
            #pragma unroll
            for (int i = 0; i < 4; ++i) {
                const int slot = i * 256 + tid;
                const int row = slot >> 3, cl = slot & 7, cg = cl ^ (row & 7);
                GLD_LDS16(&wt[(size_t)(nb + row) * E_DIM + k0 + cg * 8], &Bs[slot * 8]);
            }
            #pragma unroll
            for (int i = 0; i < 4; ++i) {
                const int slot = i * 256 + tid;
                const int row = slot >> 3, cl = slot & 7, cs = cl ^ (row & 7);
                union { unsigned int u[4]; bf16x8 v; } v8;
                v8.u[0] = pk2(ax[i][0].x, ax[i][0].y);
                v8.u[1] = pk2(ax[i][0].z, ax[i][0].w);
                v8.u[2] = pk2(ax[i][1].x, ax[i][1].y);
                v8.u[3] = pk2(ax[i][1].z, ax[i][1].w);
                *(bf16x8*)&As[row * 64 + cs * 8] = v8.v;
            }
        } else {
            const short* A = (const short*)Ap;
            __syncthreads();
            #pragma unroll
            for (int i = 0; i < 4; ++i) {
                const int slot = i * 256 + tid;
                const int row = slot >> 3, cl = slot & 7, cg = cl ^ (row & 7);
                GLD_LDS16(&A[(size_t)(bm + row) * E_DIM + k0 + cg * 8], &As[slot * 8]);
            }
            #pragma unroll
            for (int i = 0; i < 4; ++i) {
                const int slot = i * 256 + tid;
                const int row = slot >> 3, cl = slot & 7, cg = cl ^ (row & 7);
                GLD_LDS16(&wt[(size_t)(nb + row) * E_DIM + k0 + cg * 8], &Bs[slot * 8]);
            }
        }
        __syncthreads();

        #pragma unroll
        for (int ks = 0; ks < 2; ++ks) {
            bf16x8 a[4], b[4];
            #pragma unroll
            for (int mt = 0; mt < 4; ++mt) {
                const int row = wm + mt * 16 + l16;
                const int c = (ks * 4 + quad) ^ (row & 7);
                a[mt] = *(const bf16x8*)&As[row * 64 + c * 8];
            }
            #pragma unroll
            for (int nt = 0; nt < 4; ++nt) {
                const int row = wn + nt * 16 + l16;
                const int c = (ks * 4 + quad) ^ (row & 7);
                b[nt] = *(const bf16x8*)&Bs[row * 64 + c * 8];
            }
            #pragma unroll
            for (int mt = 0; mt < 4; ++mt)
                #pragma unroll
                for (int nt = 0; nt < 4; ++nt)
                    acc[mt][nt] = MFMA16(a[mt], b[nt], acc[mt][nt]);
        }
    }

    const float qscale = (wsel == 0) ? QSCALE : 1.0f;
    #pragma unroll
    for (int nt = 0; nt < 4; ++nt) {
        const int ncol = nb + wn + nt * 16 + l16;
        const float bvv = bias[ncol];
        const int h = ncol >> 6, d = ncol & (HDIM - 1);
        #pragma unroll
        for (int mt = 0; mt < 4; ++mt) {
            const int grow = bm + wm + mt * 16 + quad * 4;
            if (wsel == 1) {   // K: [B,H,S,D] scatter (B-frags need d-contig rows)
                #pragma unroll
                for (int r = 0; r < 4; ++r) {
                    const int g = grow + r, b = g >> 10, s = g & (S_LEN - 1);
                    outp[((size_t)(b * NHEADS + h) * S_LEN + s) * HDIM + d] =
                        f2bf(acc[mt][nt][r] + bvv);
                }
            } else {  // Q,V: [B,H,D,S]; 4 r-values s-consecutive -> 8B packed
                const int b = grow >> 10, s0 = grow & (S_LEN - 1);
                bf16x4 pv = pk4((acc[mt][nt][0] + bvv) * qscale,
                                (acc[mt][nt][1] + bvv) * qscale,
                                (acc[mt][nt][2] + bvv) * qscale,
                                (acc[mt][nt][3] + bvv) * qscale);
                *(bf16x4*)&outp[((size_t)(b * NHEADS + h) * HDIM + d) * S_LEN + s0] = pv;
            }
        }
    }
}

// ---------------------------------------------------------------------------
// Out projection: attn[8192,768] bf16 @ Wt_o^T + bo -> f32 out.
// 1D grid, XCD-aware (384 blocks = 6 n-strips x 64 m-strips).
// ---------------------------------------------------------------------------
__global__ __launch_bounds__(256, 3) void gemm_out_kernel(
    const short* __restrict__ A, const short* __restrict__ Wt,
    const float* __restrict__ bias, float* __restrict__ out)
{
    __shared__ __align__(16) short As[128 * 64];
    __shared__ __align__(16) short Bs[128 * 64];

    const int tid  = threadIdx.x;
    const int wave = tid >> 6, lane = tid & 63;
    const int quad = lane >> 4, l16 = lane & 15;
    const int bid = blockIdx.x;
    const int xcd = bid & 7, qq = bid >> 3;   // qq 0..47
    const int nb = (qq >> 3) * 128;           // 0..5 n-strip
    const int bm = (xcd * 8 + (qq & 7)) * 128;
    const int wm = (wave >> 1) * 64, wn = (wave & 1) * 64;

    f32x4 acc[4][4];
    #pragma unroll
    for (int mt = 0; mt < 4; ++mt)
        #pragma unroll
        for (int nt = 0; nt < 4; ++nt) acc[mt][nt] = (f32x4){0.f, 0.f, 0.f, 0.f};

    for (int k0 = 0; k0 < E_DIM; k0 += 64) {
        __syncthreads();
        #pragma unroll
        for (int i = 0; i < 4; ++i) {
            const int slot = i * 256 + tid;
            const int row = slot >> 3, cl = slot & 7, cg = cl ^ (row & 7);
            GLD_LDS16(&A[(size_t)(bm + row) * E_DIM + k0 + cg * 8], &As[slot * 8]);
        }
        #pragma unroll
        for (int i = 0; i < 4; ++i) {
            const int slot = i * 256 + tid;
            const int row = slot >> 3, cl = slot & 7, cg = cl ^ (row & 7);
            GLD_LDS16(&Wt[(size_t)(nb + row) * E_DIM + k0 + cg * 8], &Bs[slot * 8]);
        }
        __syncthreads();

        #pragma unroll
        for (int ks = 0; ks < 2; ++ks) {
            bf16x8 a[4], b[4];
            #pragma unroll
            for (int mt = 0; mt < 4; ++mt) {
                const int row = wm + mt * 16 + l16;
                const int c = (ks * 4 + quad) ^ (row & 7);
                a[mt] = *(const bf16x8*)&As[row * 64 + c * 8];
            }
            #pragma unroll
            for (int nt = 0; nt < 4; ++nt) {
                const int row = wn + nt * 16 + l16;
                const int c = (ks * 4 + quad) ^ (row & 7);
                b[nt] = *(const bf16x8*)&Bs[row * 64 + c * 8];
            }
            #pragma unroll
            for (int mt = 0; mt < 4; ++mt)
                #pragma unroll
                for (int nt = 0; nt < 4; ++nt)
                    acc[mt][nt] = MFMA16(a[mt], b[nt], acc[mt][nt]);
        }
    }

    #pragma unroll
    for (int nt = 0; nt < 4; ++nt) {
        const int ncol = nb + wn + nt * 16 + l16;
        const float bvv = bias[ncol];
        #pragma unroll
        for (int mt = 0; mt < 4; ++mt) {
            const int grow = bm + wm + mt * 16 + quad * 4;
            #pragma unroll
            for (int r = 0; r < 4; ++r)
                out[(size_t)(grow + r) * E_DIM + ncol] = acc[mt][nt][r] + bvv;
        }
    }
}

// ---------------------------------------------------------------------------
// Flash attention, S^T formulation + dbuf prefetch. Q is [B,H,D,S] now
// (transposed store in QKV): Q-frags gathered once per block via 2B loads.
// grid(96, 8): x = head -> all 8 q-blocks of a head share an XCD.
// ---------------------------------------------------------------------------
__global__ __launch_bounds__(256) void attn_kernel(
    const short* __restrict__ Q, const short* __restrict__ K,
    const short* __restrict__ V, short* __restrict__ O)
{
    __shared__ __align__(16) short Ks[2][64 * 64];   // swizzled, DMA-staged
    __shared__ __align__(16) short Vt[2][64 * 64];   // swizzled, DMA-staged

    const int tid  = threadIdx.x;
    const int wave = tid >> 6, lane = tid & 63;
    const int quad = lane >> 4, l16 = lane & 15;
    const int bh = blockIdx.x;            // head-major for XCD L2 locality
    const int q0 = blockIdx.y * 128;
    const size_t base = (size_t)bh * S_LEN * HDIM;
    const short* Qb = Q + base;   // [d][s] per head
    const short* Kb = K + base;   // [s][d]
    const short* Vb = V + base;   // [d][s]

    // Q fragments (B operand of S^T = K·Q^T): one-time 2B gathers from Q^T
    bf16x8 qa[2][2];
    #pragma unroll
    for (int mt = 0; mt < 2; ++mt)
        #pragma unroll
        for (int ks = 0; ks < 2; ++ks) {
            const int s = q0 + wave * 32 + mt * 16 + l16;
            #pragma unroll
            for (int j = 0; j < 8; ++j)
                qa[mt][ks][j] = Qb[(size_t)(ks * 32 + quad * 8 + j) * S_LEN + s];
        }

    bf16x4 ones4;
    #pragma unroll
    for (int j = 0; j < 4; ++j) ones4[j] = (short)0x3F80;   // bf16 1.0

    f32x4 oacc[2][4], lacc[2];
    #pragma unroll
    for (int mt = 0; mt < 2; ++mt) {
        #pragma unroll
        for (int nt = 0; nt < 4; ++nt) oacc[mt][nt] = (f32x4){0.f, 0.f, 0.f, 0.f};
        lacc[mt] = (f32x4){0.f, 0.f, 0.f, 0.f};
    }

    // prefetch tile 0 into buffer 0
    #pragma unroll
    for (int i = 0; i < 2; ++i) {
        const int slot = i * 256 + tid;
        const int row = slot >> 3, cl = slot & 7, cg = cl ^ (row & 7);
        GLD_LDS16(&Kb[(size_t)row * HDIM + cg * 8], &Ks[0][slot * 8]);
        GLD_LDS16(&Vb[(size_t)row * S_LEN + cg * 8], &Vt[0][slot * 8]);
    }

    for (int it = 0; it < S_LEN / 64; ++it) {
        __syncthreads();   // drains DMA(tile it); prior compute reads done
        if (it + 1 < S_LEN / 64) {       // prefetch tile it+1 (overlaps compute)
            const int kt = (it + 1) * 64, nbf = (it + 1) & 1;
            #pragma unroll
            for (int i = 0; i < 2; ++i) {
                const int slot = i * 256 + tid;
                const int row = slot >> 3, cl = slot & 7, cg = cl ^ (row & 7);
                GLD_LDS16(&Kb[(size_t)(kt + row) * HDIM + cg * 8], &Ks[nbf][slot * 8]);
                GLD_LDS16(&Vb[(size_t)row * S_LEN + kt + cg * 8], &Vt[nbf][slot * 8]);
            }
        }
        const short* ksb = Ks[it & 1];
        const short* vtb = Vt[it & 1];

        // S^T[key][q] = K·Q^T : A = K-frag (m=key), B = Q-frag (n=q)
        f32x4 sc[2][4];   // [mt][key-tile t]
        #pragma unroll
        for (int mt = 0; mt < 2; ++mt)
            #pragma unroll
            for (int t = 0; t < 4; ++t) sc[mt][t] = (f32x4){0.f, 0.f, 0.f, 0.f};
        #pragma unroll
        for (int ks = 0; ks < 2; ++ks)
            #pragma unroll
            for (int t = 0; t < 4; ++t) {
                const int row = t * 16 + l16;
                const int c = (ks * 4 + quad) ^ (row & 7);
                const bf16x8 kf = *(const bf16x8*)&ksb[row * 64 + c * 8];
                #pragma unroll
                for (int mt = 0; mt < 2; ++mt)
                    sc[mt][t] = MFMA16(kf, qa[mt][ks], sc[mt][t]);
            }

        // P = exp2(S^T): pack via v_perm (C/D row layout == K=16 A-frag k)
        bf16x4 pa16[2][4];
        #pragma unroll
        for (int mt = 0; mt < 2; ++mt)
            #pragma unroll
            for (int t = 0; t < 4; ++t)
                pa16[mt][t] = pk4(__builtin_amdgcn_exp2f(sc[mt][t][0]),
                                  __builtin_amdgcn_exp2f(sc[mt][t][1]),
                                  __builtin_amdgcn_exp2f(sc[mt][t][2]),
                                  __builtin_amdgcn_exp2f(sc[mt][t][3]));

        // O += P·V and l += P·1 via 16x16x16 MFMA (4 key-chunks of 16)
        #pragma unroll
        for (int t = 0; t < 4; ++t) {
            #pragma unroll
            for (int mt = 0; mt < 2; ++mt)
                lacc[mt] = MFMA16K16(pa16[mt][t], ones4, lacc[mt]);
            #pragma unroll
            for (int nt = 0; nt < 4; ++nt) {
                const int row = nt * 16 + l16;                    // d
                const int c = (t * 2 + (quad >> 1)) ^ (row & 7);  // swizzled chunk
                const bf16x4 vb = *(const bf16x4*)&vtb[row * 64 + c * 8 + (quad & 1) * 4];
                #pragma unroll
                for (int mt = 0; mt < 2; ++mt)
                    oacc[mt][nt] = MFMA16K16(pa16[mt][t], vb, oacc[mt][nt]);
            }
        }
    }

    const int b = bh / NHEADS, h = bh - b * NHEADS;
    #pragma unroll
    for (int mt = 0; mt < 2; ++mt)
        #pragma unroll
        for (int nt = 0; nt < 4; ++nt)
            #pragma unroll
            for (int r = 0; r < 4; ++r) {
                const int qrow = q0 + wave * 32 + mt * 16 + quad * 4 + r;
                const float val = oacc[mt][nt][r] / lacc[mt][r];
                O[(size_t)(b * S_LEN + qrow) * E_DIM + h * HDIM + nt * 16 + l16] = f2bf(val);
            }
}

extern "C" void kernel_launch(void* const* d_in, const int* in_sizes, int n_in,
                              void* d_out, int out_size, void* d_ws, size_t ws_size,
                              hipStream_t stream) {
    const float* X  = (const float*)d_in[0];
    const float* Wq = (const float*)d_in[1];
    const float* bq = (const float*)d_in[2];
    const float* Wk = (const float*)d_in[3];
    const float* bk = (const float*)d_in[4];
    const float* Wv = (const float*)d_in[5];
    const float* bv = (const float*)d_in[6];
    const float* Wo = (const float*)d_in[7];
    const float* bo = (const float*)d_in[8];
    float* out = (float*)d_out;

    const size_t t = (size_t)TOKENS * E_DIM;   // 6.29M elems
    short* q    = (short*)d_ws;                // [B,H,D,S]
    short* k    = q + t;                       // [B,H,S,D]
    short* vT   = k + t;                       // [B,H,D,S]
    short* attn = vT + t;

    const size_t fast_need = (5 * t + 4 * (size_t)WELEMS) * 2;   // ~67.6 MB
    if (ws_size >= fast_need) {
        short* wt4 = attn + t;                 // Wq^T,Wk^T,Wv^T,Wo^T (bf16)
        short* xbf = wt4 + 4 * (size_t)WELEMS; // X in bf16
        xcvt_kernel<<<(TOKENS * E_DIM / 8) / 256, 256, 0, stream>>>(X, xbf);
        transpose_w<<<dim3(12, 12, 4), 256, 0, stream>>>(Wq, Wk, Wv, Wo, wt4);
        gemm_qkv_t<false><<<1152, 256, 0, stream>>>(
            xbf, wt4, bq, bk, bv, q, k, vT);
        attn_kernel<<<dim3(BATCH * NHEADS, S_LEN / 128), 256, 0, stream>>>(q, k, vT, attn);
        gemm_out_kernel<<<384, 256, 0, stream>>>(
            attn, wt4 + 3 * (size_t)WELEMS, bo, out);
    } else {
        // fallback: cvt inside QKV kernel (ws = 50.3 MB)
        short* wt_qkv = attn;                  // overwritten later by attn out
        short* wt_o   = q;                     // q consumed before out-GEMM
        transpose_w<<<dim3(12, 12, 3), 256, 0, stream>>>(Wq, Wk, Wv, Wv, wt_qkv);
        gemm_qkv_t<true><<<1152, 256, 0, stream>>>(
            X, wt_qkv, bq, bk, bv, q, k, vT);
        attn_kernel<<<dim3(BATCH * NHEADS, S_LEN / 128), 256, 0, stream>>>(q, k, vT, attn);
        transpose_w<<<dim3(12, 12, 1), 256, 0, stream>>>(Wo, Wo, Wo, Wo, wt_o);
        gemm_out_kernel<<<384, 256, 0, stream>>>(attn, wt_o, bo, out);
    }
}